// Round 1
// baseline (387.754 us; speedup 1.0000x reference)
//
#include <hip/hip_runtime.h>
#include <math.h>

// Problem constants
constexpr int B_ = 4, C_ = 256, H4 = 96, W4 = 320, HF = 384, WF = 1280;
constexpr int CHUNKS = 5;              // 320 / 64 px per wave
constexpr float EPSV = 1e-6f;
constexpr int LOW = B_ * H4 * W4;      // 122880
constexpr int FULL = B_ * HF * WF;     // 1966080

// Phase 1: banded cosine correlation + softmax + downsampled disp -> disp_ref, conf (low-res)
__global__ __launch_bounds__(64)
void phase1(const float* __restrict__ fL, const float* __restrict__ fR,
            const float* __restrict__ D, float* __restrict__ dref,
            float* __restrict__ conf)
{
    const int bi = blockIdx.x;
    const int chunk = bi % CHUNKS;
    const int y = (bi / CHUNKS) % H4;
    const int b = bi / (CHUNKS * H4);
    const int lane = threadIdx.x;
    const int x0 = chunk * 64;
    const int x = x0 + lane;

    const size_t chanStride = (size_t)H4 * W4;                 // 30720
    const size_t rowBase = (((size_t)b * C_) * H4 + y) * W4;   // fL[b,0,y,0]

    // 7 shifted column indices with circular wrap (jnp.roll semantics)
    int col[7];
#pragma unroll
    for (int k = 0; k < 7; ++k) {
        int xx = x + k - 3;
        if (xx < 0) xx += W4;
        if (xx >= W4) xx -= W4;
        col[k] = xx;
    }
    // Halo lanes also accumulate sumsq for out-of-chunk neighbor columns
    int hx = 0;
    if (lane < 3)      { hx = x0 - 3 + lane;        if (hx < 0)   hx += W4; }
    else if (lane < 6) { hx = x0 + 64 + (lane - 3); if (hx >= W4) hx -= W4; }

    float dot[7] = {0.f,0.f,0.f,0.f,0.f,0.f,0.f};
    float ssL = 0.f, ssR = 0.f, ssH = 0.f;

    const float* pL = fL + rowBase;
    const float* pR = fR + rowBase;
#pragma unroll 4
    for (int c = 0; c < C_; ++c) {
        float a = pL[x];
        float r[7];
#pragma unroll
        for (int k = 0; k < 7; ++k) r[k] = pR[col[k]];
        if (lane < 6) { float h = pR[hx]; ssH += h * h; }
        ssL += a * a;
        ssR += r[3] * r[3];
#pragma unroll
        for (int k = 0; k < 7; ++k) dot[k] += a * r[k];
        pL += chanStride; pR += chanStride;
    }

    // Share sumsqR across the wave (+halo) so each lane can normalize all 7 neighbors
    __shared__ float sss[70];
    sss[3 + lane] = ssR;
    if (lane < 3)      sss[lane] = ssH;        // left halo: x0-3..x0-1
    else if (lane < 6) sss[64 + lane] = ssH;   // right halo: 67..69 -> x0+64..x0+66
    __syncthreads();

    const float nL = fmaxf(sqrtf(ssL), EPSV);
    float cost[7];
#pragma unroll
    for (int k = 0; k < 7; ++k) {
        // k indexes neighbor x+(k-3); reference cost[i] (d=i-3) uses neighbor x+(3-i)
        float nR = fmaxf(sqrtf(sss[lane + k]), EPSV);
        float s = dot[k] / (nL * nR);
        cost[6 - k] = s * 10.0f;               // /TEMP, TEMP=0.1
    }
    float m = cost[0];
#pragma unroll
    for (int i = 1; i < 7; ++i) m = fmaxf(m, cost[i]);
    float sum = 0.f, dsum = 0.f;
#pragma unroll
    for (int i = 0; i < 7; ++i) {
        float e = __expf(cost[i] - m);
        sum += e;
        dsum += e * (float)(i - 3);
    }
    const float delta = dsum / sum;
    const float cf = 1.0f / sum;               // max p = exp(0)/sum

    // Exact 4x downsample of disp_full: y0=4y+1,y1=4y+2, wy=wx=0.5 -> mean of 2x2, then /4
    const int Y0 = 4 * y + 1, X0 = 4 * x + 1;
    const size_t dbase = ((size_t)b * HF + Y0) * WF + X0;
    const float s4 = D[dbase] + D[dbase + 1] + D[dbase + WF] + D[dbase + WF + 1];
    const float disp0 = s4 * 0.0625f;          // (sum/4)/4

    const size_t o = ((size_t)b * H4 + y) * W4 + x;
    dref[o] = disp0 + delta;
    conf[o] = cf;
}

// Phase 2a: disp_q = disp_ref - 0.2 * Laplacian(disp_ref), zero padding
__global__ void phase2a(const float* __restrict__ dref, float* __restrict__ dq)
{
    int i = blockIdx.x * blockDim.x + threadIdx.x;
    if (i >= LOW) return;
    int x = i % W4;
    int y = (i / W4) % H4;
    float c = dref[i];
    float up = (y > 0)      ? dref[i - W4] : 0.f;
    float dn = (y < H4 - 1) ? dref[i + W4] : 0.f;
    float lf = (x > 0)      ? dref[i - 1]  : 0.f;
    float rt = (x < W4 - 1) ? dref[i + 1]  : 0.f;
    float lap = up + dn + lf + rt - 4.f * c;
    dq[i] = c - 0.2f * lap;
}

// Phase 2b: 4x bilinear upsample of disp_q (*4) and conf
__global__ void phase2b(const float* __restrict__ dq, const float* __restrict__ cf,
                        float* __restrict__ out)
{
    int i = blockIdx.x * blockDim.x + threadIdx.x;
    if (i >= FULL) return;
    int X = i % WF;
    int Y = (i / WF) % HF;
    int b = i / (WF * HF);
    float ys = fmaxf((Y + 0.5f) * 0.25f - 0.5f, 0.f);
    float xs = fmaxf((X + 0.5f) * 0.25f - 0.5f, 0.f);
    float y0f = floorf(ys), x0f = floorf(xs);
    float wy = ys - y0f, wx = xs - x0f;
    int y0 = min((int)y0f, H4 - 1);
    int x0 = min((int)x0f, W4 - 1);
    int y1 = min(y0 + 1, H4 - 1);
    int x1 = min(x0 + 1, W4 - 1);
    size_t base = (size_t)b * (H4 * W4);
    size_t i00 = base + (size_t)y0 * W4 + x0;
    size_t i01 = base + (size_t)y0 * W4 + x1;
    size_t i10 = base + (size_t)y1 * W4 + x0;
    size_t i11 = base + (size_t)y1 * W4 + x1;

    float d = (1.f - wy) * ((1.f - wx) * dq[i00] + wx * dq[i01])
            +        wy  * ((1.f - wx) * dq[i10] + wx * dq[i11]);
    float cv = (1.f - wy) * ((1.f - wx) * cf[i00] + wx * cf[i01])
             +        wy  * ((1.f - wx) * cf[i10] + wx * cf[i11]);

    out[i] = 4.0f * d;
    out[(size_t)FULL + i] = cv;
}

extern "C" void kernel_launch(void* const* d_in, const int* in_sizes, int n_in,
                              void* d_out, int out_size, void* d_ws, size_t ws_size,
                              hipStream_t stream)
{
    const float* fL = (const float*)d_in[0];
    const float* fR = (const float*)d_in[1];
    const float* D  = (const float*)d_in[2];
    float* out = (float*)d_out;
    float* ws   = (float*)d_ws;
    float* dref = ws;
    float* conf = ws + LOW;
    float* dq   = ws + 2 * LOW;

    phase1<<<B_ * H4 * CHUNKS, 64, 0, stream>>>(fL, fR, D, dref, conf);
    phase2a<<<(LOW + 255) / 256, 256, 0, stream>>>(dref, dq);
    phase2b<<<(FULL + 255) / 256, 256, 0, stream>>>(dq, conf, out);
}

// Round 2
// 307.700 us; speedup vs baseline: 1.2602x; 1.2602x over previous
//
#include <hip/hip_runtime.h>
#include <math.h>

// Problem constants
constexpr int B_ = 4, C_ = 256, H4 = 96, W4 = 320, HF = 384, WF = 1280;
constexpr int CHUNKS = 5;              // 320 / 64 px per block
constexpr float EPSV = 1e-6f;
constexpr int LOW = B_ * H4 * W4;      // 122880
constexpr int FULL = B_ * HF * WF;     // 1966080

// Phase 1: banded cosine correlation + softmax + downsampled disp -> disp_ref, conf (low-res)
// 256 threads = 4 waves; wave w reduces channels [64w, 64w+64); partials merged via LDS.
__global__ __launch_bounds__(256)
void phase1(const float* __restrict__ fL, const float* __restrict__ fR,
            const float* __restrict__ D, float* __restrict__ dref,
            float* __restrict__ conf)
{
    const int bi = blockIdx.x;
    const int chunk = bi % CHUNKS;
    const int y = (bi / CHUNKS) % H4;
    const int b = bi / (CHUNKS * H4);
    const int tid = threadIdx.x;
    const int wave = tid >> 6;
    const int lane = tid & 63;
    const int x0 = chunk * 64;
    const int x = x0 + lane;

    const size_t chanStride = (size_t)H4 * W4;                 // 30720
    const size_t rowBase = (((size_t)b * C_) * H4 + y) * W4;   // fL[b,0,y,0]

    // 7 shifted column indices with circular wrap (jnp.roll semantics)
    int col[7];
#pragma unroll
    for (int k = 0; k < 7; ++k) {
        int xx = x + k - 3;
        if (xx < 0) xx += W4;
        if (xx >= W4) xx -= W4;
        col[k] = xx;
    }
    // Halo lanes also accumulate sumsq for out-of-chunk neighbor columns
    int hx = 0;
    if (lane < 3)      { hx = x0 - 3 + lane;        if (hx < 0)   hx += W4; }
    else if (lane < 6) { hx = x0 + 64 + (lane - 3); if (hx >= W4) hx -= W4; }

    float dot[7] = {0.f,0.f,0.f,0.f,0.f,0.f,0.f};
    float ssL = 0.f, ssR = 0.f, ssH = 0.f;

    const float* pL = fL + rowBase + (size_t)(wave * 64) * chanStride;
    const float* pR = fR + rowBase + (size_t)(wave * 64) * chanStride;
#pragma unroll 4
    for (int c = 0; c < 64; ++c) {      // 64 channels per wave
        float a = pL[x];
        float r[7];
#pragma unroll
        for (int k = 0; k < 7; ++k) r[k] = pR[col[k]];
        if (lane < 6) { float h = pR[hx]; ssH += h * h; }
        ssL += a * a;
        ssR += r[3] * r[3];
#pragma unroll
        for (int k = 0; k < 7; ++k) dot[k] += a * r[k];
        pL += chanStride; pR += chanStride;
    }

    // Cross-wave reduction of 10 partials per pixel. Pad to 11 floats -> <=2-way bank alias (free).
    __shared__ float part[256][11];
    __shared__ float sss[70];
#pragma unroll
    for (int k = 0; k < 7; ++k) part[tid][k] = dot[k];
    part[tid][7] = ssL;
    part[tid][8] = ssR;
    part[tid][9] = ssH;
    __syncthreads();

    float rdot[7], rssL = 0.f;
    if (tid < 64) {
#pragma unroll
        for (int k = 0; k < 7; ++k)
            rdot[k] = part[tid][k] + part[tid + 64][k] + part[tid + 128][k] + part[tid + 192][k];
        rssL = part[tid][7] + part[tid + 64][7] + part[tid + 128][7] + part[tid + 192][7];
        float rssR = part[tid][8] + part[tid + 64][8] + part[tid + 128][8] + part[tid + 192][8];
        sss[3 + tid] = rssR;
        if (tid < 6) {
            float hh = part[tid][9] + part[tid + 64][9] + part[tid + 128][9] + part[tid + 192][9];
            if (tid < 3) sss[tid] = hh;        // left halo: x0-3..x0-1
            else         sss[64 + tid] = hh;   // right halo: 67..69 -> x0+64..x0+66
        }
    }
    __syncthreads();

    if (tid < 64) {
        const float nL = fmaxf(sqrtf(rssL), EPSV);
        float cost[7];
#pragma unroll
        for (int k = 0; k < 7; ++k) {
            // k indexes neighbor x+(k-3); reference cost[i] (d=i-3) uses neighbor x+(3-i)
            float nR = fmaxf(sqrtf(sss[tid + k]), EPSV);
            float s = rdot[k] / (nL * nR);
            cost[6 - k] = s * 10.0f;           // /TEMP, TEMP=0.1
        }
        float m = cost[0];
#pragma unroll
        for (int i = 1; i < 7; ++i) m = fmaxf(m, cost[i]);
        float sum = 0.f, dsum = 0.f;
#pragma unroll
        for (int i = 0; i < 7; ++i) {
            float e = __expf(cost[i] - m);
            sum += e;
            dsum += e * (float)(i - 3);
        }
        const float delta = dsum / sum;
        const float cf = 1.0f / sum;           // max p = exp(0)/sum

        // Exact 4x downsample of disp_full: y0=4y+1,y1=4y+2, wy=wx=0.5 -> mean of 2x2, then /4
        const int Y0 = 4 * y + 1, X0 = 4 * x + 1;
        const size_t dbase = ((size_t)b * HF + Y0) * WF + X0;
        const float s4 = D[dbase] + D[dbase + 1] + D[dbase + WF] + D[dbase + WF + 1];
        const float disp0 = s4 * 0.0625f;      // (sum/4)/4

        const size_t o = ((size_t)b * H4 + y) * W4 + x;
        dref[o] = disp0 + delta;
        conf[o] = cf;
    }
}

// dq = dref - 0.2 * Laplacian(dref) computed on the fly (zero padding)
__device__ __forceinline__ float dq_val(const float* __restrict__ dref,
                                        size_t base, int yq, int xq)
{
    size_t i = base + (size_t)yq * W4 + xq;
    float c  = dref[i];
    float up = (yq > 0)      ? dref[i - W4] : 0.f;
    float dn = (yq < H4 - 1) ? dref[i + W4] : 0.f;
    float lf = (xq > 0)      ? dref[i - 1]  : 0.f;
    float rt = (xq < W4 - 1) ? dref[i + 1]  : 0.f;
    return c - 0.2f * (up + dn + lf + rt - 4.f * c);
}

// Phase 2 (fused): 4x bilinear upsample of dq (*4) and conf
__global__ void phase2(const float* __restrict__ dref, const float* __restrict__ cf,
                       float* __restrict__ out)
{
    int i = blockIdx.x * blockDim.x + threadIdx.x;
    if (i >= FULL) return;
    int X = i % WF;
    int Y = (i / WF) % HF;
    int b = i / (WF * HF);
    float ys = fmaxf((Y + 0.5f) * 0.25f - 0.5f, 0.f);
    float xs = fmaxf((X + 0.5f) * 0.25f - 0.5f, 0.f);
    float y0f = floorf(ys), x0f = floorf(xs);
    float wy = ys - y0f, wx = xs - x0f;
    int y0 = min((int)y0f, H4 - 1);
    int x0 = min((int)x0f, W4 - 1);
    int y1 = min(y0 + 1, H4 - 1);
    int x1 = min(x0 + 1, W4 - 1);
    size_t base = (size_t)b * (H4 * W4);

    float d = (1.f - wy) * ((1.f - wx) * dq_val(dref, base, y0, x0) + wx * dq_val(dref, base, y0, x1))
            +        wy  * ((1.f - wx) * dq_val(dref, base, y1, x0) + wx * dq_val(dref, base, y1, x1));

    size_t i00 = base + (size_t)y0 * W4 + x0;
    size_t i01 = base + (size_t)y0 * W4 + x1;
    size_t i10 = base + (size_t)y1 * W4 + x0;
    size_t i11 = base + (size_t)y1 * W4 + x1;
    float cv = (1.f - wy) * ((1.f - wx) * cf[i00] + wx * cf[i01])
             +        wy  * ((1.f - wx) * cf[i10] + wx * cf[i11]);

    out[i] = 4.0f * d;
    out[(size_t)FULL + i] = cv;
}

extern "C" void kernel_launch(void* const* d_in, const int* in_sizes, int n_in,
                              void* d_out, int out_size, void* d_ws, size_t ws_size,
                              hipStream_t stream)
{
    const float* fL = (const float*)d_in[0];
    const float* fR = (const float*)d_in[1];
    const float* D  = (const float*)d_in[2];
    float* out  = (float*)d_out;
    float* ws   = (float*)d_ws;
    float* dref = ws;
    float* conf = ws + LOW;

    phase1<<<B_ * H4 * CHUNKS, 256, 0, stream>>>(fL, fR, D, dref, conf);
    phase2<<<(FULL + 255) / 256, 256, 0, stream>>>(dref, conf, out);
}

// Round 4
// 289.728 us; speedup vs baseline: 1.3383x; 1.0620x over previous
//
#include <hip/hip_runtime.h>
#include <math.h>

// Problem constants
constexpr int B_ = 4, C_ = 256, H4 = 96, W4 = 320, HF = 384, WF = 1280;
constexpr int CHUNKS = 5;              // 320 / 64 px per block
constexpr float EPSV = 1e-6f;
constexpr int LOW = B_ * H4 * W4;      // 122880
constexpr int FULL = B_ * HF * WF;     // 1966080

// Phase 1: banded cosine correlation + softmax + downsampled disp -> disp_ref, conf (low-res)
// 256 threads = 4 waves; wave w reduces channels [64w, 64w+64); partials merged via LDS.
// fR taps go global -> LDS (1 load) -> 7 ds_reads, cutting VMEM instrs/channel from 9 to ~2.1.
__global__ __launch_bounds__(256)
void phase1(const float* __restrict__ fL, const float* __restrict__ fR,
            const float* __restrict__ D, float* __restrict__ dref,
            float* __restrict__ conf)
{
    const int bi = blockIdx.x;
    const int chunk = bi % CHUNKS;
    const int y = (bi / CHUNKS) % H4;
    const int b = bi / (CHUNKS * H4);
    const int tid = threadIdx.x;
    const int wave = tid >> 6;
    const int lane = tid & 63;
    const int x0 = chunk * 64;
    const int x = x0 + lane;

    const size_t chanStride = (size_t)H4 * W4;                 // 30720
    const size_t rowBase = (((size_t)b * C_) * H4 + y) * W4;   // fL[b,0,y,0]

    // Halo lanes (0..5) also fetch the out-of-chunk neighbor columns (circular wrap, jnp.roll)
    int hx = 0, hslot = 0;
    const bool isHalo = (lane < 6);
    if (lane < 3)      { hx = x0 - 3 + lane;        if (hx < 0)   hx += W4; hslot = lane; }
    else if (lane < 6) { hx = x0 + 64 + (lane - 3); if (hx >= W4) hx -= W4; hslot = 64 + lane; } // 67..69

    float dot[7] = {0.f,0.f,0.f,0.f,0.f,0.f,0.f};
    float ssL = 0.f, ssR = 0.f, ssH = 0.f;

    // Per-wave staging buffer: [0..2]=left halo, [3..66]=chunk, [67..69]=right halo
    __shared__ float stage[4][72];
    float* const sw = stage[wave];

    const float* pLx = fL + rowBase + (size_t)(wave * 64) * chanStride + x;
    const float* pRx = fR + rowBase + (size_t)(wave * 64) * chanStride + x;
    const float* pRh = fR + rowBase + (size_t)(wave * 64) * chanStride + hx;

#pragma unroll 4
    for (int c = 0; c < 64; ++c) {      // 64 channels per wave
        const float a  = *pLx;
        const float rv = *pRx;
        sw[3 + lane] = rv;
        if (isHalo) {
            const float h = *pRh;
            sw[hslot] = h;
            ssH += h * h;
        }
        // Per-wave LDS ops; drain so cross-lane writes are visible to this wave's reads.
        __asm__ volatile("s_waitcnt lgkmcnt(0)" ::: "memory");
        float r[7];
#pragma unroll
        for (int k = 0; k < 7; ++k) r[k] = sw[lane + k];
        ssL += a * a;
        ssR += rv * rv;
#pragma unroll
        for (int k = 0; k < 7; ++k) dot[k] += a * r[k];
        pLx += chanStride; pRx += chanStride; pRh += chanStride;
    }

    // Cross-wave reduction of 10 partials per pixel. Pad to 11 floats -> <=2-way bank alias (free).
    __shared__ float part[256][11];
    __shared__ float sss[70];
#pragma unroll
    for (int k = 0; k < 7; ++k) part[tid][k] = dot[k];
    part[tid][7] = ssL;
    part[tid][8] = ssR;
    part[tid][9] = ssH;
    __syncthreads();

    float rdot[7], rssL = 0.f;
    if (tid < 64) {
#pragma unroll
        for (int k = 0; k < 7; ++k)
            rdot[k] = part[tid][k] + part[tid + 64][k] + part[tid + 128][k] + part[tid + 192][k];
        rssL = part[tid][7] + part[tid + 64][7] + part[tid + 128][7] + part[tid + 192][7];
        float rssR = part[tid][8] + part[tid + 64][8] + part[tid + 128][8] + part[tid + 192][8];
        sss[3 + tid] = rssR;
        if (tid < 6) {
            float hh = part[tid][9] + part[tid + 64][9] + part[tid + 128][9] + part[tid + 192][9];
            if (tid < 3) sss[tid] = hh;        // left halo: x0-3..x0-1
            else         sss[64 + tid] = hh;   // right halo: 67..69 -> x0+64..x0+66
        }
    }
    __syncthreads();

    if (tid < 64) {
        const float nL = fmaxf(sqrtf(rssL), EPSV);
        float cost[7];
#pragma unroll
        for (int k = 0; k < 7; ++k) {
            // k indexes neighbor x+(k-3); reference cost[i] (d=i-3) uses neighbor x+(3-i)
            float nR = fmaxf(sqrtf(sss[tid + k]), EPSV);
            float s = rdot[k] / (nL * nR);
            cost[6 - k] = s * 10.0f;           // /TEMP, TEMP=0.1
        }
        float m = cost[0];
#pragma unroll
        for (int i = 1; i < 7; ++i) m = fmaxf(m, cost[i]);
        float sum = 0.f, dsum = 0.f;
#pragma unroll
        for (int i = 0; i < 7; ++i) {
            float e = __expf(cost[i] - m);
            sum += e;
            dsum += e * (float)(i - 3);
        }
        const float delta = dsum / sum;
        const float cf = 1.0f / sum;           // max p = exp(0)/sum

        // Exact 4x downsample of disp_full: y0=4y+1,y1=4y+2, wy=wx=0.5 -> mean of 2x2, then /4
        const int xpix = x0 + tid;             // full low-res column (BUG FIX: was 4*tid+1)
        const int Y0 = 4 * y + 1, X0 = 4 * xpix + 1;
        const size_t dbase = ((size_t)b * HF + Y0) * WF + X0;
        const float s4 = D[dbase] + D[dbase + 1] + D[dbase + WF] + D[dbase + WF + 1];
        const float disp0 = s4 * 0.0625f;      // (sum/4)/4

        const size_t o = ((size_t)b * H4 + y) * W4 + xpix;
        dref[o] = disp0 + delta;
        conf[o] = cf;
    }
}

// dq = dref - 0.2 * Laplacian(dref) computed on the fly (zero padding)
__device__ __forceinline__ float dq_val(const float* __restrict__ dref,
                                        size_t base, int yq, int xq)
{
    size_t i = base + (size_t)yq * W4 + xq;
    float c  = dref[i];
    float up = (yq > 0)      ? dref[i - W4] : 0.f;
    float dn = (yq < H4 - 1) ? dref[i + W4] : 0.f;
    float lf = (xq > 0)      ? dref[i - 1]  : 0.f;
    float rt = (xq < W4 - 1) ? dref[i + 1]  : 0.f;
    return c - 0.2f * (up + dn + lf + rt - 4.f * c);
}

// Phase 2 (fused): 4x bilinear upsample of dq (*4) and conf
__global__ void phase2(const float* __restrict__ dref, const float* __restrict__ cf,
                       float* __restrict__ out)
{
    int i = blockIdx.x * blockDim.x + threadIdx.x;
    if (i >= FULL) return;
    int X = i % WF;
    int Y = (i / WF) % HF;
    int b = i / (WF * HF);
    float ys = fmaxf((Y + 0.5f) * 0.25f - 0.5f, 0.f);
    float xs = fmaxf((X + 0.5f) * 0.25f - 0.5f, 0.f);
    float y0f = floorf(ys), x0f = floorf(xs);
    float wy = ys - y0f, wx = xs - x0f;
    int y0 = min((int)y0f, H4 - 1);
    int x0 = min((int)x0f, W4 - 1);
    int y1 = min(y0 + 1, H4 - 1);
    int x1 = min(x0 + 1, W4 - 1);
    size_t base = (size_t)b * (H4 * W4);

    float d = (1.f - wy) * ((1.f - wx) * dq_val(dref, base, y0, x0) + wx * dq_val(dref, base, y0, x1))
            +        wy  * ((1.f - wx) * dq_val(dref, base, y1, x0) + wx * dq_val(dref, base, y1, x1));

    size_t i00 = base + (size_t)y0 * W4 + x0;
    size_t i01 = base + (size_t)y0 * W4 + x1;
    size_t i10 = base + (size_t)y1 * W4 + x0;
    size_t i11 = base + (size_t)y1 * W4 + x1;
    float cv = (1.f - wy) * ((1.f - wx) * cf[i00] + wx * cf[i01])
             +        wy  * ((1.f - wx) * cf[i10] + wx * cf[i11]);

    out[i] = 4.0f * d;
    out[(size_t)FULL + i] = cv;
}

extern "C" void kernel_launch(void* const* d_in, const int* in_sizes, int n_in,
                              void* d_out, int out_size, void* d_ws, size_t ws_size,
                              hipStream_t stream)
{
    const float* fL = (const float*)d_in[0];
    const float* fR = (const float*)d_in[1];
    const float* D  = (const float*)d_in[2];
    float* out  = (float*)d_out;
    float* ws   = (float*)d_ws;
    float* dref = ws;
    float* conf = ws + LOW;

    phase1<<<B_ * H4 * CHUNKS, 256, 0, stream>>>(fL, fR, D, dref, conf);
    phase2<<<(FULL + 255) / 256, 256, 0, stream>>>(dref, conf, out);
}

// Round 5
// 286.819 us; speedup vs baseline: 1.3519x; 1.0101x over previous
//
#include <hip/hip_runtime.h>
#include <math.h>

// Problem constants
constexpr int B_ = 4, C_ = 256, H4 = 96, W4 = 320, HF = 384, WF = 1280;
constexpr int CHUNKS = 5;              // 320 / 64 px per block
constexpr float EPSV = 1e-6f;
constexpr int LOW = B_ * H4 * W4;      // 122880
constexpr int FULL = B_ * HF * WF;     // 1966080

// Phase 1: banded cosine correlation + softmax + downsampled disp -> disp_ref, conf (low-res)
// 256 threads = 4 waves; wave w reduces channels [64w, 64w+64).
// 4-channel batches staged as float4 in wave-private LDS (b128 ops, conflict-free);
// next batch's 12 global loads issued before the lgkmcnt-only wait -> deep MLP, no
// compiler memory barrier in the hot loop.
__global__ __launch_bounds__(256)
void phase1(const float* __restrict__ fL, const float* __restrict__ fR,
            const float* __restrict__ D, float* __restrict__ dref,
            float* __restrict__ conf)
{
    const int bi = blockIdx.x;
    const int chunk = bi % CHUNKS;
    const int y = (bi / CHUNKS) % H4;
    const int b = bi / (CHUNKS * H4);
    const int tid = threadIdx.x;
    const int wave = tid >> 6;
    const int lane = tid & 63;
    const int x0 = chunk * 64;
    const int x = x0 + lane;

    const size_t chanStride = (size_t)H4 * W4;                 // 30720
    const size_t rowBase = (((size_t)b * C_) * H4 + y) * W4;   // fL[b,0,y,0]

    // Halo columns (circular wrap, jnp.roll). Non-halo lanes point at their own
    // column (valid address, same cache line) -> unconditional load, masked WRITE.
    int hx = x, hslot = 0;
    const bool isHalo = (lane < 6);
    if (lane < 3)      { hx = x0 - 3 + lane;        if (hx < 0)   hx += W4; hslot = lane; }
    else if (lane < 6) { hx = x0 + 64 + (lane - 3); if (hx >= W4) hx -= W4; hslot = 64 + lane; } // 67..69

    float dot[7] = {0.f,0.f,0.f,0.f,0.f,0.f,0.f};
    float ssL = 0.f, ssR = 0.f, ssH = 0.f;

    // Per-wave staging: [0..2]=left halo, [3..66]=chunk, [67..69]=right halo; float4 = 4 channels
    __shared__ float4 stage4[4][72];
    float4* const sw = stage4[wave];

    const float* pLb = fL + rowBase + (size_t)(wave * 64) * chanStride;
    const float* pRb = fR + rowBase + (size_t)(wave * 64) * chanStride;

    float aa[4], rr[4], hh[4];
    size_t off = 0;
#pragma unroll
    for (int j = 0; j < 4; ++j) {       // prologue: batch 0 (channels 0..3)
        aa[j] = pLb[off + x]; rr[j] = pRb[off + x]; hh[j] = pRb[off + hx];
        off += chanStride;
    }

#pragma unroll 4
    for (int it = 0; it < 16; ++it) {   // 16 batches x 4 channels = 64 channels per wave
        const float ca0 = aa[0], ca1 = aa[1], ca2 = aa[2], ca3 = aa[3];
        const float4 rq = make_float4(rr[0], rr[1], rr[2], rr[3]);
        const float4 hq = make_float4(hh[0], hh[1], hh[2], hh[3]);

        sw[3 + lane] = rq;              // ds_write_b128
        if (isHalo) sw[hslot] = hq;     // masked halo write

        if (it < 15) {                  // issue NEXT batch's globals before the LDS drain
#pragma unroll
            for (int j = 0; j < 4; ++j) {
                aa[j] = pLb[off + x]; rr[j] = pRb[off + x]; hh[j] = pRb[off + hx];
                off += chanStride;
            }
        }

        // lgkmcnt(0) only: vmcnt untouched -> global loads stay in flight.
        __builtin_amdgcn_s_waitcnt(0xC07F);

#pragma unroll
        for (int k = 0; k < 7; ++k) {   // 7 x ds_read_b128, 16B-aligned, conflict-free
            const float4 t = sw[lane + k];
            dot[k] += ca0 * t.x + ca1 * t.y + ca2 * t.z + ca3 * t.w;
        }
        ssL += ca0 * ca0 + ca1 * ca1 + ca2 * ca2 + ca3 * ca3;
        ssR += rq.x * rq.x + rq.y * rq.y + rq.z * rq.z + rq.w * rq.w;
        ssH += hq.x * hq.x + hq.y * hq.y + hq.z * hq.z + hq.w * hq.w; // garbage for non-halo lanes, never read
    }

    // Cross-wave reduction of 10 partials per pixel. Pad to 11 floats -> <=2-way bank alias (free).
    __shared__ float part[256][11];
    __shared__ float sss[70];
#pragma unroll
    for (int k = 0; k < 7; ++k) part[tid][k] = dot[k];
    part[tid][7] = ssL;
    part[tid][8] = ssR;
    part[tid][9] = ssH;
    __syncthreads();

    float rdot[7], rssL = 0.f;
    if (tid < 64) {
#pragma unroll
        for (int k = 0; k < 7; ++k)
            rdot[k] = part[tid][k] + part[tid + 64][k] + part[tid + 128][k] + part[tid + 192][k];
        rssL = part[tid][7] + part[tid + 64][7] + part[tid + 128][7] + part[tid + 192][7];
        float rssR = part[tid][8] + part[tid + 64][8] + part[tid + 128][8] + part[tid + 192][8];
        sss[3 + tid] = rssR;
        if (tid < 6) {
            float hh2 = part[tid][9] + part[tid + 64][9] + part[tid + 128][9] + part[tid + 192][9];
            if (tid < 3) sss[tid] = hh2;       // left halo: x0-3..x0-1
            else         sss[64 + tid] = hh2;  // right halo: 67..69 -> x0+64..x0+66
        }
    }
    __syncthreads();

    if (tid < 64) {
        const float nL = fmaxf(sqrtf(rssL), EPSV);
        float cost[7];
#pragma unroll
        for (int k = 0; k < 7; ++k) {
            // k indexes neighbor x+(k-3); reference cost[i] (d=i-3) uses neighbor x+(3-i)
            float nR = fmaxf(sqrtf(sss[tid + k]), EPSV);
            float s = rdot[k] / (nL * nR);
            cost[6 - k] = s * 10.0f;           // /TEMP, TEMP=0.1
        }
        float m = cost[0];
#pragma unroll
        for (int i = 1; i < 7; ++i) m = fmaxf(m, cost[i]);
        float sum = 0.f, dsum = 0.f;
#pragma unroll
        for (int i = 0; i < 7; ++i) {
            float e = __expf(cost[i] - m);
            sum += e;
            dsum += e * (float)(i - 3);
        }
        const float delta = dsum / sum;
        const float cf = 1.0f / sum;           // max p = exp(0)/sum

        // Exact 4x downsample of disp_full: y0=4y+1,y1=4y+2, wy=wx=0.5 -> mean of 2x2, then /4
        const int xpix = x0 + tid;             // full low-res column
        const int Y0 = 4 * y + 1, X0 = 4 * xpix + 1;
        const size_t dbase = ((size_t)b * HF + Y0) * WF + X0;
        const float s4 = D[dbase] + D[dbase + 1] + D[dbase + WF] + D[dbase + WF + 1];
        const float disp0 = s4 * 0.0625f;      // (sum/4)/4

        const size_t o = ((size_t)b * H4 + y) * W4 + xpix;
        dref[o] = disp0 + delta;
        conf[o] = cf;
    }
}

// dq = dref - 0.2 * Laplacian(dref) computed on the fly (zero padding)
__device__ __forceinline__ float dq_val(const float* __restrict__ dref,
                                        size_t base, int yq, int xq)
{
    size_t i = base + (size_t)yq * W4 + xq;
    float c  = dref[i];
    float up = (yq > 0)      ? dref[i - W4] : 0.f;
    float dn = (yq < H4 - 1) ? dref[i + W4] : 0.f;
    float lf = (xq > 0)      ? dref[i - 1]  : 0.f;
    float rt = (xq < W4 - 1) ? dref[i + 1]  : 0.f;
    return c - 0.2f * (up + dn + lf + rt - 4.f * c);
}

// Phase 2 (fused): 4x bilinear upsample of dq (*4) and conf
__global__ void phase2(const float* __restrict__ dref, const float* __restrict__ cf,
                       float* __restrict__ out)
{
    int i = blockIdx.x * blockDim.x + threadIdx.x;
    if (i >= FULL) return;
    int X = i % WF;
    int Y = (i / WF) % HF;
    int b = i / (WF * HF);
    float ys = fmaxf((Y + 0.5f) * 0.25f - 0.5f, 0.f);
    float xs = fmaxf((X + 0.5f) * 0.25f - 0.5f, 0.f);
    float y0f = floorf(ys), x0f = floorf(xs);
    float wy = ys - y0f, wx = xs - x0f;
    int y0 = min((int)y0f, H4 - 1);
    int x0 = min((int)x0f, W4 - 1);
    int y1 = min(y0 + 1, H4 - 1);
    int x1 = min(x0 + 1, W4 - 1);
    size_t base = (size_t)b * (H4 * W4);

    float d = (1.f - wy) * ((1.f - wx) * dq_val(dref, base, y0, x0) + wx * dq_val(dref, base, y0, x1))
            +        wy  * ((1.f - wx) * dq_val(dref, base, y1, x0) + wx * dq_val(dref, base, y1, x1));

    size_t i00 = base + (size_t)y0 * W4 + x0;
    size_t i01 = base + (size_t)y0 * W4 + x1;
    size_t i10 = base + (size_t)y1 * W4 + x0;
    size_t i11 = base + (size_t)y1 * W4 + x1;
    float cv = (1.f - wy) * ((1.f - wx) * cf[i00] + wx * cf[i01])
             +        wy  * ((1.f - wx) * cf[i10] + wx * cf[i11]);

    out[i] = 4.0f * d;
    out[(size_t)FULL + i] = cv;
}

extern "C" void kernel_launch(void* const* d_in, const int* in_sizes, int n_in,
                              void* d_out, int out_size, void* d_ws, size_t ws_size,
                              hipStream_t stream)
{
    const float* fL = (const float*)d_in[0];
    const float* fR = (const float*)d_in[1];
    const float* D  = (const float*)d_in[2];
    float* out  = (float*)d_out;
    float* ws   = (float*)d_ws;
    float* dref = ws;
    float* conf = ws + LOW;

    phase1<<<B_ * H4 * CHUNKS, 256, 0, stream>>>(fL, fR, D, dref, conf);
    phase2<<<(FULL + 255) / 256, 256, 0, stream>>>(dref, conf, out);
}